// Round 6
// baseline (25.897 us; speedup 1.0000x reference)
//
#include <hip/hip_runtime.h>
#include <stdint.h>

#define BB   32
#define HH   64
#define WW   2048
#define HOUT 128     // 2*(HH-1)+2
#define NB1  2048
#define NT   256

typedef float f4 __attribute__((ext_vector_type(4)));

// ---- K1: global-min partials only ----------------------------------------
__global__ void __launch_bounds__(NT)
k1_min(const float* __restrict__ x, float* __restrict__ partial) {
    const int tid = threadIdx.x;
    const f4* x4 = (const f4*)x;
    float m = 3.4e38f;
    int i = blockIdx.x * NT + tid;
    #pragma unroll
    for (int it = 0; it < (BB * HH * WW / 4) / (NB1 * NT); ++it, i += NB1 * NT) {
        f4 v = x4[i];
        m = fminf(fminf(v.x, v.y), fminf(fminf(v.z, v.w), m));
    }
    #pragma unroll
    for (int off = 32; off > 0; off >>= 1)
        m = fminf(m, __shfl_down(m, off, 64));
    __shared__ float smem[4];
    if ((tid & 63) == 0) smem[tid >> 6] = m;
    __syncthreads();
    if (tid == 0)
        partial[blockIdx.x] =
            fminf(fminf(smem[0], smem[1]), fminf(smem[2], smem[3]));
}

// ---- K2: entire output (copy rows + interpolated rows) -------------------
// 8192 blocks = 32 batches * 128 rows * 2 half-rows. XCD-chunked swizzle so
// adjacent rows (which share x rows) run on the same XCD's L2.
__global__ void __launch_bounds__(NT)
k2_all(const float* __restrict__ x, float* __restrict__ out,
       const float* __restrict__ partial) {
    const int tid = threadIdx.x;

    int bid  = blockIdx.x;
    int work = (bid & 7) * 1024 + (bid >> 3);   // 8192/8 = 1024 per XCD
    int b    = work >> 8;          // 256 half-rows per batch image
    int rem  = work & 255;
    int ho   = rem >> 1;           // output row 0..127
    int w0   = ((rem & 1) << 10) + (tid << 2);

    float* orow = out + ((size_t)(b * HOUT) + ho) * WW + w0;
    int h = ho >> 1;               // even: src row; odd: top row; 126,127 -> 63

    if ((ho & 1) == 0 || ho == 127) {
        f4 v = *(const f4*)(x + ((size_t)(b * HH) + h) * WW + w0);
        __builtin_nontemporal_store(v, (f4*)orow);
        return;
    }

    // block-uniform branch: safe to reduce partials with __syncthreads here
    __shared__ float smem[4];
    float p = 3.4e38f;
    #pragma unroll
    for (int k = 0; k < NB1 / NT; ++k)
        p = fminf(p, partial[tid + k * NT]);
    #pragma unroll
    for (int off = 32; off > 0; off >>= 1)
        p = fminf(p, __shfl_down(p, off, 64));
    if ((tid & 63) == 0) smem[tid >> 6] = p;
    __syncthreads();
    // padding zeros are part of the window tensor -> gmin = min(min(x), 0)
    const float gmin = fminf(
        fminf(fminf(smem[0], smem[1]), fminf(smem[2], smem[3])), 0.0f);

    const float* rA = x + ((size_t)(b * HH) + h) * WW + w0;
    const float* rB = rA + WW;

    f4 a  = *(const f4*)rA;
    f4 c4 = *(const f4*)rB;
    float aL = (w0 > 0)      ? rA[-1] : 0.0f;
    float bL = (w0 > 0)      ? rB[-1] : 0.0f;
    float aR = (w0 + 4 < WW) ? rA[4]  : 0.0f;
    float bR = (w0 + 4 < WW) ? rB[4]  : 0.0f;

    float av[6] = {aL, a.x, a.y, a.z, a.w, aR};
    float bv[6] = {bL, c4.x, c4.y, c4.z, c4.w, bR};

    const float BASE_D = 0.49306869139523979f;  // exp(-sqrt(2)/2)
    const float BASE_C = 0.60653065971263342f;  // exp(-0.5)

    f4 res;
    #pragma unroll
    for (int c = 0; c < 4; ++c) {
        float num = 0.0f, den = 0.0f;
        float vs[6] = {av[c], av[c + 1], av[c + 2],
                       bv[c], bv[c + 1], bv[c + 2]};
        const float bs[6] = {BASE_D, BASE_C, BASE_D, BASE_D, BASE_C, BASE_D};
        #pragma unroll
        for (int k = 0; k < 6; ++k) {
            float wv = vs[k];
            float e  = __expf(wv - gmin);
            float wi = bs[k] * 2.0f * __builtin_amdgcn_rcpf(1.0f + e);
            wi = (wv != 0.0f) ? wi : 0.0f;
            num += wv * wi;
            den += wi;
        }
        den = (den == 0.0f) ? 1.0f : den;
        res[c] = num * __builtin_amdgcn_rcpf(den);
    }

    __builtin_nontemporal_store(res, (f4*)orow);
}

extern "C" void kernel_launch(void* const* d_in, const int* in_sizes, int n_in,
                              void* d_out, int out_size, void* d_ws, size_t ws_size,
                              hipStream_t stream) {
    const float* x = (const float*)d_in[0];
    float* out = (float*)d_out;
    float* partial = (float*)d_ws;   // NB1 floats = 8 KiB scratch

    hipLaunchKernelGGL(k1_min, dim3(NB1), dim3(NT), 0, stream, x, partial);
    hipLaunchKernelGGL(k2_all, dim3(BB * HOUT * 2), dim3(NT), 0, stream,
                       x, out, partial);
}

// Round 7
// 18.917 us; speedup vs baseline: 1.3690x; 1.3690x over previous
//
#include <hip/hip_runtime.h>
#include <stdint.h>

#define BB   32
#define HH   64
#define WW   2048
#define HOUT 128     // 2*(HH-1)+2
#define NB1  1024
#define NT   256

typedef float f4 __attribute__((ext_vector_type(4)));

// ---- K1: global-min partials + copy rows ---------------------------------
// Reads all of x once (f4): accumulates per-block min AND writes the copy
// rows (out[2h] = x[h]; h==63 also duplicates into row 127). One HBM read
// serves both consumers.
__global__ void __launch_bounds__(NT)
k1_min_copy(const float* __restrict__ x, float* __restrict__ out,
            float* __restrict__ partial) {
    const int tid = threadIdx.x;
    const f4* x4 = (const f4*)x;
    float m = 3.4e38f;

    int i = blockIdx.x * NT + tid;
    #pragma unroll
    for (int it = 0; it < (BB * HH * WW / 4) / (NB1 * NT); ++it, i += NB1 * NT) {
        f4 v = x4[i];
        m = fminf(fminf(v.x, v.y), fminf(fminf(v.z, v.w), m));

        int b   = i >> 15;        // HH*WW/4 = 32768 f4 per batch image
        int rem = i & 32767;
        int h   = rem >> 9;       // 512 f4 per row
        int wq  = rem & 511;

        f4* o = (f4*)(out + ((size_t)(b * HOUT) + 2 * h) * WW) + wq;
        __builtin_nontemporal_store(v, o);
        if (h == 63) {            // duplicate last row (2*63=126 above, plus 127)
            f4* o2 = (f4*)(out + ((size_t)(b * HOUT) + 127) * WW) + wq;
            __builtin_nontemporal_store(v, o2);
        }
    }

    #pragma unroll
    for (int off = 32; off > 0; off >>= 1)
        m = fminf(m, __shfl_down(m, off, 64));
    __shared__ float smem[4];
    if ((tid & 63) == 0) smem[tid >> 6] = m;
    __syncthreads();
    if (tid == 0)
        partial[blockIdx.x] =
            fminf(fminf(smem[0], smem[1]), fminf(smem[2], smem[3]));
}

// ---- K2: odd (interpolated) rows -----------------------------------------
// grid = 32*63*2 = 4032 blocks = 8 XCD chunks of 504. Each block: half of
// one odd output row. x loads issued FIRST (hide latency under the partial
// reduction); XCD-chunked swizzle keeps neighboring rows in one XCD's L2.
__global__ void __launch_bounds__(NT)
k2_pixels(const float* __restrict__ x, float* __restrict__ out,
          const float* __restrict__ partial) {
    __shared__ float smem[4];
    const int tid = threadIdx.x;

    // bijective XCD swizzle: 4032 % 8 == 0, chunk = 504 consecutive works
    int work = (blockIdx.x & 7) * 504 + (blockIdx.x >> 3);
    int b    = work / 126;        // 63 odd rows * 2 half-rows per batch
    int r    = work - b * 126;
    int h    = r >> 1;            // x top row 0..62
    int w0   = ((r & 1) << 10) + (tid << 2);

    // ---- issue x loads first (independent of partial reduction) ----
    const float* rA = x + ((size_t)(b * HH) + h) * WW + w0;
    const float* rB = rA + WW;
    f4 a  = *(const f4*)rA;
    f4 c4 = *(const f4*)rB;
    float aL = (w0 > 0)      ? rA[-1] : 0.0f;
    float bL = (w0 > 0)      ? rB[-1] : 0.0f;
    float aR = (w0 + 4 < WW) ? rA[4]  : 0.0f;
    float bR = (w0 + 4 < WW) ? rB[4]  : 0.0f;

    // ---- block-wide reduction of the 1024 partials (L2-resident) ----
    float p = fminf(fminf(partial[tid], partial[tid + 256]),
                    fminf(partial[tid + 512], partial[tid + 768]));
    #pragma unroll
    for (int off = 32; off > 0; off >>= 1)
        p = fminf(p, __shfl_down(p, off, 64));
    if ((tid & 63) == 0) smem[tid >> 6] = p;
    __syncthreads();
    // padding zeros are part of the window tensor -> gmin = min(min(x), 0)
    const float gmin = fminf(
        fminf(fminf(smem[0], smem[1]), fminf(smem[2], smem[3])), 0.0f);

    float av[6] = {aL, a.x, a.y, a.z, a.w, aR};
    float bv[6] = {bL, c4.x, c4.y, c4.z, c4.w, bR};

    const float BASE_D = 0.49306869139523979f;  // exp(-sqrt(2)/2)
    const float BASE_C = 0.60653065971263342f;  // exp(-0.5)

    f4 res;
    #pragma unroll
    for (int c = 0; c < 4; ++c) {
        float num = 0.0f, den = 0.0f;
        float vs[6] = {av[c], av[c + 1], av[c + 2],
                       bv[c], bv[c + 1], bv[c + 2]};
        const float bs[6] = {BASE_D, BASE_C, BASE_D, BASE_D, BASE_C, BASE_D};
        #pragma unroll
        for (int k = 0; k < 6; ++k) {
            float wv = vs[k];
            float e  = __expf(wv - gmin);
            float wi = bs[k] * 2.0f * __builtin_amdgcn_rcpf(1.0f + e);
            wi = (wv != 0.0f) ? wi : 0.0f;
            num += wv * wi;
            den += wi;
        }
        den = (den == 0.0f) ? 1.0f : den;
        res[c] = num * __builtin_amdgcn_rcpf(den);
    }

    f4* o = (f4*)(out + ((size_t)(b * HOUT) + 2 * h + 1) * WW + w0);
    __builtin_nontemporal_store(res, o);
}

extern "C" void kernel_launch(void* const* d_in, const int* in_sizes, int n_in,
                              void* d_out, int out_size, void* d_ws, size_t ws_size,
                              hipStream_t stream) {
    const float* x = (const float*)d_in[0];
    float* out = (float*)d_out;
    float* partial = (float*)d_ws;   // 1024 floats

    hipLaunchKernelGGL(k1_min_copy, dim3(NB1), dim3(NT), 0, stream,
                       x, out, partial);
    hipLaunchKernelGGL(k2_pixels, dim3(BB * 63 * 2), dim3(NT), 0, stream,
                       x, out, partial);
}